// Round 2
// baseline (1255.095 us; speedup 1.0000x reference)
//
#include <hip/hip_runtime.h>
#include <hip/hip_bf16.h>
#include <math.h>

// Problem constants (from reference)
#define N_NODES  1000000
#define C_IN     128
#define HID      32
#define OUTF     16
#define NSRC1    600000
#define NDST1    80000
#define E1       1280000
#define NDST2    8000
#define E2       80000

// ---------------------------------------------------------------------------
// K1: p[s] = x[n_id[s]] @ W1 — register-tiled GEMM.
// Block 256 = 4 waves; each wave owns a 32-row tile (wave-private LDS chunk,
// no barriers in the k-loop). k processed in 4 chunks of 32:
//   stage: 8 lanes x 128B contiguous per row (coalesced), written transposed
//          into A_t[k][m] (stride 36 floats: 16B-aligned, 2-way bank alias = free)
//   compute: thread (m4,o4) does 4x4 tile: per k, 2x ds_read_b128 + 16 FMA.
// W1 (128x32 row-major) staged once in LDS, b128 reads along o.
// ---------------------------------------------------------------------------
#define K1_STRIDE 36

__global__ __launch_bounds__(256) void k1_transform(
    const float* __restrict__ x, const int* __restrict__ n_id,
    const float* __restrict__ W1, float* __restrict__ p)
{
    __shared__ float W_s[C_IN * HID];            // 16 KB, row-major
    __shared__ float A_t[4][32 * K1_STRIDE];     // 4 x 4.6 KB, per-wave

    for (int i = threadIdx.x; i < C_IN * HID; i += 256) W_s[i] = W1[i];
    __syncthreads();   // only barrier in the kernel

    const int wave = threadIdx.x >> 6;
    const int lane = threadIdx.x & 63;
    const int gwave = blockIdx.x * 4 + wave;     // 32-row tiles
    if (gwave >= NSRC1 / 32) return;             // after the barrier
    const int s0 = gwave * 32;

    float* At = A_t[wave];

    // staging mapping: j in 0..3 ; idx = j*64+lane ; mrow = idx>>3 ; f = idx&7
    // lane loads float4 at x[n_id[s0+mrow]]*128 + c*32 + f*4
    int   mrow[4]; int f8[4]; const float* rowp[4];
    #pragma unroll
    for (int j = 0; j < 4; ++j) {
        int idx = j * 64 + lane;
        mrow[j] = idx >> 3;
        f8[j]   = idx & 7;
        rowp[j] = x + (size_t)n_id[s0 + mrow[j]] * C_IN + f8[j] * 4;
    }

    const int m4 = lane >> 3;    // 0..7 -> rows m4*4 .. m4*4+3
    const int o4 = lane & 7;     // 0..7 -> cols o4*4 .. o4*4+3

    float acc[4][4];
    #pragma unroll
    for (int i = 0; i < 4; ++i)
        #pragma unroll
        for (int j = 0; j < 4; ++j) acc[i][j] = 0.f;

    // prefetch chunk 0
    float4 v[4];
    #pragma unroll
    for (int j = 0; j < 4; ++j) v[j] = *(const float4*)(rowp[j]);

    #pragma unroll
    for (int c = 0; c < 4; ++c) {
        // write staged regs -> transposed LDS
        #pragma unroll
        for (int j = 0; j < 4; ++j) {
            int kb = f8[j] * 4;                  // local k base
            int m  = mrow[j];
            At[(kb + 0) * K1_STRIDE + m] = v[j].x;
            At[(kb + 1) * K1_STRIDE + m] = v[j].y;
            At[(kb + 2) * K1_STRIDE + m] = v[j].z;
            At[(kb + 3) * K1_STRIDE + m] = v[j].w;
        }
        // prefetch next chunk (global latency hidden under compute)
        if (c < 3) {
            #pragma unroll
            for (int j = 0; j < 4; ++j)
                v[j] = *(const float4*)(rowp[j] + (c + 1) * 32);
        }
        // compute chunk (same-wave DS ops are in-order: RAW/WAR safe, no barrier)
        #pragma unroll 4
        for (int k = 0; k < 32; ++k) {
            float4 a = *(const float4*)&At[k * K1_STRIDE + m4 * 4];
            float4 w = *(const float4*)&W_s[(c * 32 + k) * HID + o4 * 4];
            acc[0][0] += a.x * w.x; acc[0][1] += a.x * w.y; acc[0][2] += a.x * w.z; acc[0][3] += a.x * w.w;
            acc[1][0] += a.y * w.x; acc[1][1] += a.y * w.y; acc[1][2] += a.y * w.z; acc[1][3] += a.y * w.w;
            acc[2][0] += a.z * w.x; acc[2][1] += a.z * w.y; acc[2][2] += a.z * w.z; acc[2][3] += a.z * w.w;
            acc[3][0] += a.w * w.x; acc[3][1] += a.w * w.y; acc[3][2] += a.w * w.z; acc[3][3] += a.w * w.w;
        }
    }

    // epilogue: 4 float4 stores, rows s0+m4*4+i, cols o4*4..+3
    #pragma unroll
    for (int i = 0; i < 4; ++i) {
        float4 o = make_float4(acc[i][0], acc[i][1], acc[i][2], acc[i][3]);
        *(float4*)&p[(size_t)(s0 + m4 * 4 + i) * HID + o4 * 4] = o;
    }
}

// ---------------------------------------------------------------------------
// K2: scatter layer-1 messages. 8 lanes per edge, float4 per lane.
// ---------------------------------------------------------------------------
__global__ __launch_bounds__(256) void k2_scatter1(
    const int* __restrict__ src1, const int* __restrict__ dst1,
    const float* __restrict__ p, float* __restrict__ agg1,
    float* __restrict__ cnt1)
{
    const int gid = blockIdx.x * 256 + threadIdx.x;
    const int e = gid >> 3;
    const int f4 = gid & 7;
    if (e >= E1) return;
    const int s = src1[e];
    const int d = dst1[e];
    float4 vv = *(const float4*)&p[(size_t)s * HID + f4 * 4];
    float* ap = &agg1[(size_t)d * HID + f4 * 4];
    atomicAdd(ap + 0, vv.x);
    atomicAdd(ap + 1, vv.y);
    atomicAdd(ap + 2, vv.z);
    atomicAdd(ap + 3, vv.w);
    if (f4 == 0) atomicAdd(&cnt1[d], 1.0f);
}

// ---------------------------------------------------------------------------
// K3: q[d] = relu(agg1[d]/max(cnt1[d],1) + b1) @ W2
// ---------------------------------------------------------------------------
__global__ __launch_bounds__(256) void k3_finalize1(
    const float* __restrict__ agg1, const float* __restrict__ cnt1,
    const float* __restrict__ b1, const float* __restrict__ W2,
    float* __restrict__ q)
{
    __shared__ float w2s[HID * OUTF];
    __shared__ float b1s[HID];
    for (int i = threadIdx.x; i < HID * OUTF; i += 256) w2s[i] = W2[i];
    if (threadIdx.x < HID) b1s[threadIdx.x] = b1[threadIdx.x];
    __syncthreads();

    const int gid = blockIdx.x * 256 + threadIdx.x;
    const int d = gid >> 4;
    const int j = gid & 15;
    if (d >= NDST1) return;

    const float inv = 1.0f / fmaxf(cnt1[d], 1.0f);
    float acc = 0.f;
    #pragma unroll
    for (int i = 0; i < HID; ++i) {
        float a = fmaxf(agg1[(size_t)d * HID + i] * inv + b1s[i], 0.f);
        acc += a * w2s[i * OUTF + j];
    }
    q[(size_t)d * OUTF + j] = acc;
}

// ---------------------------------------------------------------------------
// K4: scatter layer-2 messages. 4 lanes per edge, float4 per lane.
// ---------------------------------------------------------------------------
__global__ __launch_bounds__(256) void k4_scatter2(
    const int* __restrict__ src2, const int* __restrict__ dst2,
    const float* __restrict__ q, float* __restrict__ agg2,
    float* __restrict__ cnt2)
{
    const int gid = blockIdx.x * 256 + threadIdx.x;
    const int e = gid >> 2;
    const int f4 = gid & 3;
    if (e >= E2) return;
    const int s = src2[e];
    const int d = dst2[e];
    float4 vv = *(const float4*)&q[(size_t)s * OUTF + f4 * 4];
    float* ap = &agg2[(size_t)d * OUTF + f4 * 4];
    atomicAdd(ap + 0, vv.x);
    atomicAdd(ap + 1, vv.y);
    atomicAdd(ap + 2, vv.z);
    atomicAdd(ap + 3, vv.w);
    if (f4 == 0) atomicAdd(&cnt2[d], 1.0f);
}

// ---------------------------------------------------------------------------
// K5: out[v] = log_softmax(agg2[v]/max(cnt2[v],1) + b2). One thread per v.
// ---------------------------------------------------------------------------
__global__ __launch_bounds__(256) void k5_logsoftmax(
    const float* __restrict__ agg2, const float* __restrict__ cnt2,
    const float* __restrict__ b2, float* __restrict__ out)
{
    const int v = blockIdx.x * 256 + threadIdx.x;
    if (v >= NDST2) return;
    const float inv = 1.0f / fmaxf(cnt2[v], 1.0f);
    float z[OUTF];
    float m = -INFINITY;
    #pragma unroll
    for (int j = 0; j < OUTF; ++j) {
        z[j] = agg2[(size_t)v * OUTF + j] * inv + b2[j];
        m = fmaxf(m, z[j]);
    }
    float s = 0.f;
    #pragma unroll
    for (int j = 0; j < OUTF; ++j) s += expf(z[j] - m);
    const float lse = m + logf(s);
    #pragma unroll
    for (int j = 0; j < OUTF; ++j) out[(size_t)v * OUTF + j] = z[j] - lse;
}

// ---------------------------------------------------------------------------
// Workspace layout (bytes):
//   p    @ 0          : 600000*32*4 = 76,800,000
//   agg1 @ 76,800,000 : 80000*32*4  = 10,240,000
//   cnt1 @ 87,040,000 : 80000*4     =    320,000
//   agg2 @ 87,360,000 : 8000*16*4   =    512,000
//   cnt2 @ 87,872,000 : 8000*4      =     32,000
//   q    @ 87,904,000 : 80000*16*4  =  5,120,000   (total ~93 MB)
// agg1..cnt2 contiguous -> single memset of 11,104,000 B.
// ---------------------------------------------------------------------------
extern "C" void kernel_launch(void* const* d_in, const int* in_sizes, int n_in,
                              void* d_out, int out_size, void* d_ws, size_t ws_size,
                              hipStream_t stream)
{
    const float* x    = (const float*)d_in[0];
    const int*   n_id = (const int*)  d_in[1];
    const int*   src1 = (const int*)  d_in[2];
    const int*   dst1 = (const int*)  d_in[3];
    const int*   src2 = (const int*)  d_in[4];
    const int*   dst2 = (const int*)  d_in[5];
    const float* W1   = (const float*)d_in[6];
    const float* b1   = (const float*)d_in[7];
    const float* W2   = (const float*)d_in[8];
    const float* b2   = (const float*)d_in[9];
    float* out = (float*)d_out;

    char* ws = (char*)d_ws;
    float* p    = (float*)(ws + 0);
    float* agg1 = (float*)(ws + 76800000);
    float* cnt1 = (float*)(ws + 87040000);
    float* agg2 = (float*)(ws + 87360000);
    float* cnt2 = (float*)(ws + 87872000);
    float* q    = (float*)(ws + 87904000);

    hipMemsetAsync(agg1, 0, 11104000, stream);

    // 18750 wave-tiles of 32 rows, 4 per block
    k1_transform <<<(NSRC1 / 32 + 3) / 4, 256, 0, stream>>>(x, n_id, W1, p);
    k2_scatter1  <<<(E1 * 8 + 255) / 256, 256, 0, stream>>>(src1, dst1, p, agg1, cnt1);
    k3_finalize1 <<<(NDST1 * 16 + 255) / 256, 256, 0, stream>>>(agg1, cnt1, b1, W2, q);
    k4_scatter2  <<<(E2 * 4 + 255) / 256, 256, 0, stream>>>(src2, dst2, q, agg2, cnt2);
    k5_logsoftmax<<<(NDST2 + 255) / 256, 256, 0, stream>>>(agg2, cnt2, b2, out);
}

// Round 3
// 851.078 us; speedup vs baseline: 1.4747x; 1.4747x over previous
//
#include <hip/hip_runtime.h>
#include <hip/hip_bf16.h>
#include <math.h>

// Problem constants (from reference)
#define N_NODES  1000000
#define C_IN     128
#define HID      32
#define OUTF     16
#define NSRC1    600000
#define NDST1    80000
#define E1       1280000
#define NDST2    8000
#define E2       80000

#define NB1 313          // ceil(NDST1/256)

// ---------------------------------------------------------------------------
// K1: p[s] = x[n_id[s]] @ W1 — register-tiled GEMM (unchanged from R2).
// ---------------------------------------------------------------------------
#define K1_STRIDE 36

__global__ __launch_bounds__(256) void k1_transform(
    const float* __restrict__ x, const int* __restrict__ n_id,
    const float* __restrict__ W1, float* __restrict__ p)
{
    __shared__ float W_s[C_IN * HID];            // 16 KB, row-major
    __shared__ float A_t[4][32 * K1_STRIDE];     // per-wave transposed A tile

    for (int i = threadIdx.x; i < C_IN * HID; i += 256) W_s[i] = W1[i];
    __syncthreads();

    const int wave = threadIdx.x >> 6;
    const int lane = threadIdx.x & 63;
    const int gwave = blockIdx.x * 4 + wave;
    if (gwave >= NSRC1 / 32) return;
    const int s0 = gwave * 32;

    float* At = A_t[wave];

    int   mrow[4]; int f8[4]; const float* rowp[4];
    #pragma unroll
    for (int j = 0; j < 4; ++j) {
        int idx = j * 64 + lane;
        mrow[j] = idx >> 3;
        f8[j]   = idx & 7;
        rowp[j] = x + (size_t)n_id[s0 + mrow[j]] * C_IN + f8[j] * 4;
    }

    const int m4 = lane >> 3;
    const int o4 = lane & 7;

    float acc[4][4];
    #pragma unroll
    for (int i = 0; i < 4; ++i)
        #pragma unroll
        for (int j = 0; j < 4; ++j) acc[i][j] = 0.f;

    float4 v[4];
    #pragma unroll
    for (int j = 0; j < 4; ++j) v[j] = *(const float4*)(rowp[j]);

    #pragma unroll
    for (int c = 0; c < 4; ++c) {
        #pragma unroll
        for (int j = 0; j < 4; ++j) {
            int kb = f8[j] * 4;
            int m  = mrow[j];
            At[(kb + 0) * K1_STRIDE + m] = v[j].x;
            At[(kb + 1) * K1_STRIDE + m] = v[j].y;
            At[(kb + 2) * K1_STRIDE + m] = v[j].z;
            At[(kb + 3) * K1_STRIDE + m] = v[j].w;
        }
        if (c < 3) {
            #pragma unroll
            for (int j = 0; j < 4; ++j)
                v[j] = *(const float4*)(rowp[j] + (c + 1) * 32);
        }
        #pragma unroll 4
        for (int k = 0; k < 32; ++k) {
            float4 a = *(const float4*)&At[k * K1_STRIDE + m4 * 4];
            float4 w = *(const float4*)&W_s[(c * 32 + k) * HID + o4 * 4];
            acc[0][0] += a.x * w.x; acc[0][1] += a.x * w.y; acc[0][2] += a.x * w.z; acc[0][3] += a.x * w.w;
            acc[1][0] += a.y * w.x; acc[1][1] += a.y * w.y; acc[1][2] += a.y * w.z; acc[1][3] += a.y * w.w;
            acc[2][0] += a.z * w.x; acc[2][1] += a.z * w.y; acc[2][2] += a.z * w.z; acc[2][3] += a.z * w.w;
            acc[3][0] += a.w * w.x; acc[3][1] += a.w * w.y; acc[3][2] += a.w * w.z; acc[3][3] += a.w * w.w;
        }
    }

    #pragma unroll
    for (int i = 0; i < 4; ++i) {
        float4 o = make_float4(acc[i][0], acc[i][1], acc[i][2], acc[i][3]);
        *(float4*)&p[(size_t)(s0 + m4 * 4 + i) * HID + o4 * 4] = o;
    }
}

// ---------------------------------------------------------------------------
// CSR build: histogram -> 2-level exclusive scan -> bucket scatter of src ids
// ---------------------------------------------------------------------------
__global__ __launch_bounds__(256) void k_hist(
    const int* __restrict__ dst1, int* __restrict__ deg)
{
    const int e = blockIdx.x * 256 + threadIdx.x;
    if (e < E1) atomicAdd(&deg[dst1[e]], 1);
}

__global__ __launch_bounds__(256) void k_scan1(
    const int* __restrict__ deg, int* __restrict__ row_start,
    int* __restrict__ bsums)
{
    __shared__ int s[256];
    const int i = blockIdx.x * 256 + threadIdx.x;
    const int v = (i < NDST1) ? deg[i] : 0;
    s[threadIdx.x] = v;
    __syncthreads();
    #pragma unroll
    for (int off = 1; off < 256; off <<= 1) {
        int t = (threadIdx.x >= off) ? s[threadIdx.x - off] : 0;
        __syncthreads();
        s[threadIdx.x] += t;
        __syncthreads();
    }
    if (i < NDST1) row_start[i] = s[threadIdx.x] - v;   // exclusive, intra-block
    if (threadIdx.x == 255) bsums[blockIdx.x] = s[255];
}

__global__ __launch_bounds__(512) void k_scan2(int* __restrict__ bsums)
{
    __shared__ int s[512];
    const int v = (threadIdx.x < NB1) ? bsums[threadIdx.x] : 0;
    s[threadIdx.x] = v;
    __syncthreads();
    #pragma unroll
    for (int off = 1; off < 512; off <<= 1) {
        int t = (threadIdx.x >= off) ? s[threadIdx.x - off] : 0;
        __syncthreads();
        s[threadIdx.x] += t;
        __syncthreads();
    }
    if (threadIdx.x < NB1) bsums[threadIdx.x] = s[threadIdx.x] - v; // exclusive
}

__global__ __launch_bounds__(256) void k_apply(
    int* __restrict__ row_start, const int* __restrict__ bsums,
    int* __restrict__ cursor)
{
    const int i = blockIdx.x * 256 + threadIdx.x;
    if (i < NDST1) {
        int r = row_start[i] + bsums[blockIdx.x];
        row_start[i] = r;
        cursor[i] = r;
    }
}

__global__ __launch_bounds__(256) void k_bucket(
    const int* __restrict__ src1, const int* __restrict__ dst1,
    int* __restrict__ cursor, int* __restrict__ sorted_src)
{
    const int e = blockIdx.x * 256 + threadIdx.x;
    if (e >= E1) return;
    const int d = dst1[e];
    const int pos = atomicAdd(&cursor[d], 1);
    sorted_src[pos] = src1[e];
}

// ---------------------------------------------------------------------------
// K_gather1: per dst, gather+mean p rows, relu(+b1), then @W2 -> q. Fuses the
// old k2 (scatter) and k3 (finalize). 32 lanes per dst, 8 dsts per block.
// Cross-lane h -> GEMV via per-group LDS (same-wave DS ops are in-order; the
// R2 k1 transpose relied on the same property and validated).
// ---------------------------------------------------------------------------
__global__ __launch_bounds__(256) void k_gather1(
    const int* __restrict__ row_start, const int* __restrict__ deg,
    const int* __restrict__ sorted_src, const float* __restrict__ p,
    const float* __restrict__ b1, const float* __restrict__ W2,
    float* __restrict__ q)
{
    __shared__ float w2s[HID * OUTF];
    __shared__ float b1s[HID];
    __shared__ float hbuf[8][HID];
    for (int i = threadIdx.x; i < HID * OUTF; i += 256) w2s[i] = W2[i];
    if (threadIdx.x < HID) b1s[threadIdx.x] = b1[threadIdx.x];
    __syncthreads();

    const int g = threadIdx.x >> 5;
    const int f = threadIdx.x & 31;
    const int d = blockIdx.x * 8 + g;
    if (d >= NDST1) return;

    const int start = row_start[d];
    const int dg    = deg[d];

    float acc = 0.f;
    int i = 0;
    for (; i + 2 <= dg; i += 2) {            // 2-way MLP
        int s0 = sorted_src[start + i];
        int s1 = sorted_src[start + i + 1];
        acc += p[(size_t)s0 * HID + f] + p[(size_t)s1 * HID + f];
    }
    if (i < dg) acc += p[(size_t)sorted_src[start + i] * HID + f];

    const float h = fmaxf(acc / (float)max(dg, 1) + b1s[f], 0.f);
    hbuf[g][f] = h;
    // same-wave LDS RAW: in-order DS pipe, no barrier needed
    if (f < OUTF) {
        float oacc = 0.f;
        #pragma unroll
        for (int k = 0; k < HID; ++k) oacc += hbuf[g][k] * w2s[k * OUTF + f];
        q[(size_t)d * OUTF + f] = oacc;
    }
}

// ---------------------------------------------------------------------------
// K4: layer-2 scatter, R1 layout (16 lanes/edge, 1 atomic each — same-line
// coalesced). Only 1.28M atomics.
// ---------------------------------------------------------------------------
__global__ __launch_bounds__(256) void k4_scatter2(
    const int* __restrict__ src2, const int* __restrict__ dst2,
    const float* __restrict__ q, float* __restrict__ agg2,
    float* __restrict__ cnt2)
{
    const int gid = blockIdx.x * 256 + threadIdx.x;
    const int e = gid >> 4;
    const int f = gid & 15;
    if (e >= E2) return;
    const int s = src2[e];
    const int d = dst2[e];
    atomicAdd(&agg2[(size_t)d * OUTF + f], q[(size_t)s * OUTF + f]);
    if (f == 0) atomicAdd(&cnt2[d], 1.0f);
}

// ---------------------------------------------------------------------------
// K5: log_softmax
// ---------------------------------------------------------------------------
__global__ __launch_bounds__(256) void k5_logsoftmax(
    const float* __restrict__ agg2, const float* __restrict__ cnt2,
    const float* __restrict__ b2, float* __restrict__ out)
{
    const int v = blockIdx.x * 256 + threadIdx.x;
    if (v >= NDST2) return;
    const float inv = 1.0f / fmaxf(cnt2[v], 1.0f);
    float z[OUTF];
    float m = -INFINITY;
    #pragma unroll
    for (int j = 0; j < OUTF; ++j) {
        z[j] = agg2[(size_t)v * OUTF + j] * inv + b2[j];
        m = fmaxf(m, z[j]);
    }
    float s = 0.f;
    #pragma unroll
    for (int j = 0; j < OUTF; ++j) s += expf(z[j] - m);
    const float lse = m + logf(s);
    #pragma unroll
    for (int j = 0; j < OUTF; ++j) out[(size_t)v * OUTF + j] = z[j] - lse;
}

// ---------------------------------------------------------------------------
// Workspace layout (bytes), total ~88.5 MB:
//   p          @ 0          : 76,800,000
//   sorted_src @ 76,800,000 :  5,120,000
//   deg        @ 81,920,000 :    320,000  ┐
//   agg2       @ 82,240,000 :    512,000  ├ zeroed block: 864,000 B
//   cnt2       @ 82,752,000 :     32,000  ┘
//   row_start  @ 82,784,000 :    320,032
//   cursor     @ 83,104,032 :    320,000
//   bsums      @ 83,424,032 :      2,048
//   q          @ 83,426,080 :  5,120,000   (ends 88,546,080)
// ---------------------------------------------------------------------------
extern "C" void kernel_launch(void* const* d_in, const int* in_sizes, int n_in,
                              void* d_out, int out_size, void* d_ws, size_t ws_size,
                              hipStream_t stream)
{
    const float* x    = (const float*)d_in[0];
    const int*   n_id = (const int*)  d_in[1];
    const int*   src1 = (const int*)  d_in[2];
    const int*   dst1 = (const int*)  d_in[3];
    const int*   src2 = (const int*)  d_in[4];
    const int*   dst2 = (const int*)  d_in[5];
    const float* W1   = (const float*)d_in[6];
    const float* b1   = (const float*)d_in[7];
    const float* W2   = (const float*)d_in[8];
    const float* b2   = (const float*)d_in[9];
    float* out = (float*)d_out;

    char* ws = (char*)d_ws;
    float* p          = (float*)(ws + 0);
    int*   sorted_src = (int*)  (ws + 76800000);
    int*   deg        = (int*)  (ws + 81920000);
    float* agg2       = (float*)(ws + 82240000);
    float* cnt2       = (float*)(ws + 82752000);
    int*   row_start  = (int*)  (ws + 82784000);
    int*   cursor     = (int*)  (ws + 83104032);
    int*   bsums      = (int*)  (ws + 83424032);
    float* q          = (float*)(ws + 83426080);

    // zero deg + agg2 + cnt2 (contiguous)
    hipMemsetAsync(deg, 0, 864000, stream);

    k1_transform <<<(NSRC1 / 32 + 3) / 4, 256, 0, stream>>>(x, n_id, W1, p);

    k_hist   <<<(E1 + 255) / 256, 256, 0, stream>>>(dst1, deg);
    k_scan1  <<<NB1, 256, 0, stream>>>(deg, row_start, bsums);
    k_scan2  <<<1, 512, 0, stream>>>(bsums);
    k_apply  <<<NB1, 256, 0, stream>>>(row_start, bsums, cursor);
    k_bucket <<<(E1 + 255) / 256, 256, 0, stream>>>(src1, dst1, cursor, sorted_src);

    k_gather1<<<(NDST1 + 7) / 8, 256, 0, stream>>>(row_start, deg, sorted_src,
                                                   p, b1, W2, q);

    k4_scatter2  <<<(E2 * 16 + 255) / 256, 256, 0, stream>>>(src2, dst2, q, agg2, cnt2);
    k5_logsoftmax<<<(NDST2 + 255) / 256, 256, 0, stream>>>(agg2, cnt2, b2, out);
}